// Round 1
// baseline (1994.035 us; speedup 1.0000x reference)
//
#include <hip/hip_runtime.h>
#include <math.h>

#define BNS 0.9999950000374997f  /* 1/sqrt(1+1e-5) */

// ---------------------------------------------------------------- utilities
static __device__ __forceinline__ float wredf(float v) {
    #pragma unroll
    for (int o = 32; o; o >>= 1) v += __shfl_xor(v, o);
    return v;
}

// ---------------------------------------------------------------- min of dst
__global__ void k_min(const int* __restrict__ d, int E, int* __restrict__ mn) {
    int i = blockIdx.x * blockDim.x + threadIdx.x;
    int v = 0x7FFFFFFF;
    for (; i < E; i += gridDim.x * blockDim.x) v = min(v, d[i]);
    #pragma unroll
    for (int o = 32; o; o >>= 1) v = min(v, __shfl_xor(v, o));
    if ((threadIdx.x & 63) == 0) atomicMin(mn, v);
}

// ---------------------------------------------------------------- histogram
__global__ void k_count(const int* __restrict__ dst, const int* __restrict__ src,
                        const int* __restrict__ minbuf, int E,
                        int* __restrict__ cntM, int* __restrict__ cntN) {
    int i = blockIdx.x * blockDim.x + threadIdx.x;
    if (i >= E) return;
    int mn = minbuf[0];
    atomicAdd(&cntM[dst[i] - mn], 1);
    atomicAdd(&cntN[src[i]], 1);
}

// ---------------------------------------------------------------- exclusive scan (single block, 1024 thr, wave-based)
__global__ __launch_bounds__(1024) void k_scan(const int* __restrict__ cnt, int n,
                                               int* __restrict__ rowptr) {
    __shared__ int wsum[16];
    __shared__ int carry;
    int tid = threadIdx.x, lane = tid & 63, wv = tid >> 6;
    if (tid == 0) carry = 0;
    __syncthreads();
    for (int base = 0; base < n; base += 1024) {
        int i = base + tid;
        int v = (i < n) ? cnt[i] : 0;
        int x = v;
        #pragma unroll
        for (int o = 1; o < 64; o <<= 1) { int t = __shfl_up(x, o); if (lane >= o) x += t; }
        if (lane == 63) wsum[wv] = x;
        __syncthreads();
        if (tid < 16) {
            int s = wsum[tid];
            #pragma unroll
            for (int o = 1; o < 16; o <<= 1) { int t = __shfl_up(s, o); if (tid >= o) s += t; }
            wsum[tid] = s;
        }
        __syncthreads();
        int woff = (wv == 0) ? 0 : wsum[wv - 1];
        int excl = carry + woff + x - v;
        if (i < n) rowptr[i] = excl;
        __syncthreads();
        if (tid == 1023) carry = carry + wsum[15];
        __syncthreads();
    }
    if (tid == 0) rowptr[n] = carry;
}

// ---------------------------------------------------------------- CSR fill
__global__ void k_fill(const int* __restrict__ dst, const int* __restrict__ src,
                       const int* __restrict__ minbuf, int E,
                       const int* __restrict__ rpM, int* __restrict__ curM, int* __restrict__ csrD,
                       const int* __restrict__ rpN, int* __restrict__ curN, int* __restrict__ csrS) {
    int i = blockIdx.x * blockDim.x + threadIdx.x;
    if (i >= E) return;
    int mn = minbuf[0];
    int d = dst[i] - mn;
    int p = rpM[d] + atomicAdd(&curM[d], 1);
    csrD[p] = i;
    int s = src[i];
    int q = rpN[s] + atomicAdd(&curN[s], 1);
    csrS[q] = i;
}

// ---------------------------------------------------------------- fused (preop -> LN) -> 128x128 matmul -> +bias -> relu
// 256 threads, 16 rows per block. A staged in LDS; thread owns (col, 8 rows).
__global__ __launch_bounds__(256) void k_mm128(
        const float* __restrict__ in, int S,
        int preop, int do_ln,
        const float* __restrict__ lng, const float* __restrict__ lnb,
        const float* __restrict__ W, const float* __restrict__ bias,
        float* __restrict__ out) {
    __shared__ float A[16][128];
    int tid = threadIdx.x, lane = tid & 63, wv = tid >> 6;
    int base = blockIdx.x * 16;
    #pragma unroll
    for (int i = 0; i < 4; i++) {
        int r = wv * 4 + i, row = base + r;
        float2 v = make_float2(0.f, 0.f);
        if (row < S) v = *(const float2*)(in + (size_t)row * 128 + (lane << 1));
        if (preop) { v.x = fmaxf(v.x * BNS, 0.f); v.y = fmaxf(v.y * BNS, 0.f); }
        if (do_ln) {
            float s = v.x + v.y, q = v.x * v.x + v.y * v.y;
            s = wredf(s); q = wredf(q);
            float m  = s * (1.f / 128.f);
            float var = q * (1.f / 128.f) - m * m;
            float rs = rsqrtf(var + 1e-5f);
            int c = lane << 1;
            v.x = (v.x - m) * rs * lng[c]     + lnb[c];
            v.y = (v.y - m) * rs * lng[c + 1] + lnb[c + 1];
        }
        A[r][lane * 2]     = v.x;
        A[r][lane * 2 + 1] = v.y;
    }
    __syncthreads();
    int col = tid & 127, half = tid >> 7;
    float acc[8];
    #pragma unroll
    for (int r = 0; r < 8; r++) acc[r] = 0.f;
    for (int k = 0; k < 128; k += 4) {
        float w0 = W[(k + 0) * 128 + col];
        float w1 = W[(k + 1) * 128 + col];
        float w2 = W[(k + 2) * 128 + col];
        float w3 = W[(k + 3) * 128 + col];
        #pragma unroll
        for (int r = 0; r < 8; r++) {
            const float4 a = *(const float4*)&A[half * 8 + r][k];
            acc[r] = fmaf(a.x, w0, fmaf(a.y, w1, fmaf(a.z, w2, fmaf(a.w, w3, acc[r]))));
        }
    }
    float bb = bias[col];
    #pragma unroll
    for (int r = 0; r < 8; r++) {
        int row = base + half * 8 + r;
        if (row < S) out[(size_t)row * 128 + col] = fmaxf(acc[r] + bb, 0.f);
    }
}

// ---------------------------------------------------------------- CSR gather aggregation (norm-weighted mean)
__global__ __launch_bounds__(256) void k_aggregate(
        const float* __restrict__ h, const int* __restrict__ rowptr,
        const int* __restrict__ eids, const int* __restrict__ gidx,
        const int* __restrict__ minbuf, int sub_min,
        const float* __restrict__ norm, float* __restrict__ agg, int T) {
    int row = blockIdx.x * 4 + (threadIdx.x >> 6);
    if (row >= T) return;
    int lane = threadIdx.x & 63;
    int mn = sub_min ? minbuf[0] : 0;
    int beg = rowptr[row], end = rowptr[row + 1];
    float a0 = 0.f, a1 = 0.f;
    for (int p = beg; p < end; ++p) {
        int e = eids[p];
        int srow = gidx[e] - mn;
        float w = norm[e];
        const float2 v = *(const float2*)(h + (size_t)srow * 128 + (lane << 1));
        a0 = fmaf(w, v.x, a0);
        a1 = fmaf(w, v.y, a1);
    }
    float invc = 1.f / fmaxf((float)(end - beg), 1.f);
    float2 o; o.x = a0 * invc; o.y = a1 * invc;
    *(float2*)(agg + (size_t)row * 128 + (lane << 1)) = o;
}

// ---------------------------------------------------------------- column stats (colsum[128] + total sumsq at [128])
__global__ __launch_bounds__(256) void k_colstats(const float* __restrict__ x, int n,
                                                  float* __restrict__ stats) {
    int c = threadIdx.x & 127;
    int r = blockIdx.x * 2 + (threadIdx.x >> 7);
    float acc = 0.f, asq = 0.f;
    for (; r < n; r += gridDim.x * 2) {
        float v = x[(size_t)r * 128 + c];
        acc += v; asq += v * v;
    }
    atomicAdd(&stats[c], acc);
    __shared__ float red[4];
    asq = wredf(asq);
    if ((threadIdx.x & 63) == 0) red[threadIdx.x >> 6] = asq;
    __syncthreads();
    if (threadIdx.x == 0) atomicAdd(&stats[128], red[0] + red[1] + red[2] + red[3]);
}

// ---------------------------------------------------------------- finalize center_scale stats: mu[c] in-place, inv at [128]
__global__ void k_finalize(float* __restrict__ stats, int n) {
    int c = threadIdx.x;  // 128 threads
    float mu = stats[c] / (float)n;
    stats[c] = mu;
    float m2 = mu * mu;
    #pragma unroll
    for (int o = 32; o; o >>= 1) m2 += __shfl_xor(m2, o);
    __shared__ float ws2[2];
    if ((c & 63) == 0) ws2[c >> 6] = m2;
    __syncthreads();
    if (c == 0) {
        float musq = ws2[0] + ws2[1];
        float msn = stats[128] / (float)n - musq;  // mean ||x_i - mu||^2
        stats[128] = rsqrtf(1e-5f + msn);
    }
}

// ---------------------------------------------------------------- apply center_scale
__global__ void k_apply(const float* __restrict__ in, const float* __restrict__ stats,
                        float* __restrict__ out, int n) {
    size_t i = ((size_t)blockIdx.x * blockDim.x + threadIdx.x) * 4;
    size_t tot = (size_t)n * 128;
    if (i >= tot) return;
    float inv = stats[128];
    int c = (int)(i & 127);
    float4 v = *(const float4*)(in + i);
    v.x = (v.x - stats[c])     * inv;
    v.y = (v.y - stats[c + 1]) * inv;
    v.z = (v.z - stats[c + 2]) * inv;
    v.w = (v.w - stats[c + 3]) * inv;
    *(float4*)(out + i) = v;
}

// ---------------------------------------------------------------- classifier: [M,384]@[384,256] + b -> LN -> relu -> @[256,2] + b
// 8 rows per block, 256 threads.
__global__ __launch_bounds__(256) void k_classifier(
        const float* __restrict__ e0, const float* __restrict__ e1, const float* __restrict__ e2,
        const float* __restrict__ W1, const float* __restrict__ b1,
        const float* __restrict__ lng, const float* __restrict__ lnb,
        const float* __restrict__ W2, const float* __restrict__ b2,
        float* __restrict__ out, int M) {
    __shared__ float A[8][384];
    __shared__ float SC[8][256];
    int tid = threadIdx.x;
    int base = blockIdx.x * 8;
    for (int idx = tid; idx < 8 * 384; idx += 256) {
        int r = idx / 384, c = idx % 384;
        int row = base + r;
        float v = 0.f;
        if (row < M) {
            if (c < 128)      v = e0[(size_t)row * 128 + c];
            else if (c < 256) v = e1[(size_t)row * 128 + (c - 128)];
            else              v = e2[(size_t)row * 128 + (c - 256)];
        }
        A[r][c] = v;
    }
    __syncthreads();
    int j = tid;  // 0..255
    float acc[8];
    #pragma unroll
    for (int r = 0; r < 8; r++) acc[r] = 0.f;
    for (int k = 0; k < 384; k += 4) {
        float w0 = W1[(size_t)(k + 0) * 256 + j];
        float w1 = W1[(size_t)(k + 1) * 256 + j];
        float w2 = W1[(size_t)(k + 2) * 256 + j];
        float w3 = W1[(size_t)(k + 3) * 256 + j];
        #pragma unroll
        for (int r = 0; r < 8; r++) {
            const float4 a = *(const float4*)&A[r][k];
            acc[r] = fmaf(a.x, w0, fmaf(a.y, w1, fmaf(a.z, w2, fmaf(a.w, w3, acc[r]))));
        }
    }
    float bb = b1[j];
    #pragma unroll
    for (int r = 0; r < 8; r++) SC[r][j] = acc[r] + bb;
    __syncthreads();
    int wv = tid >> 6, lane = tid & 63;
    #pragma unroll
    for (int rr = 0; rr < 2; rr++) {
        int r = wv * 2 + rr;
        int row = base + r;
        float v0 = SC[r][lane], v1 = SC[r][lane + 64], v2 = SC[r][lane + 128], v3 = SC[r][lane + 192];
        float s = wredf(v0 + v1 + v2 + v3);
        float q = wredf(v0 * v0 + v1 * v1 + v2 * v2 + v3 * v3);
        float m = s * (1.f / 256.f);
        float var = q * (1.f / 256.f) - m * m;
        float rs = rsqrtf(var + 1e-5f);
        float h0 = fmaxf((v0 - m) * rs * lng[lane]       + lnb[lane],       0.f);
        float h1 = fmaxf((v1 - m) * rs * lng[lane + 64]  + lnb[lane + 64],  0.f);
        float h2 = fmaxf((v2 - m) * rs * lng[lane + 128] + lnb[lane + 128], 0.f);
        float h3 = fmaxf((v3 - m) * rs * lng[lane + 192] + lnb[lane + 192], 0.f);
        float p0 = h0 * W2[lane * 2]           + h1 * W2[(lane + 64) * 2]
                 + h2 * W2[(lane + 128) * 2]   + h3 * W2[(lane + 192) * 2];
        float p1 = h0 * W2[lane * 2 + 1]       + h1 * W2[(lane + 64) * 2 + 1]
                 + h2 * W2[(lane + 128) * 2 + 1] + h3 * W2[(lane + 192) * 2 + 1];
        p0 = wredf(p0);
        p1 = wredf(p1);
        if (lane == 0 && row < M) {
            out[(size_t)row * 2]     = p0 + b2[0];
            out[(size_t)row * 2 + 1] = p1 + b2[1];
        }
    }
}

// ================================================================ host
extern "C" void kernel_launch(void* const* d_in, const int* in_sizes, int n_in,
                              void* d_out, int out_size, void* d_ws, size_t ws_size,
                              hipStream_t stream) {
    const float* x    = (const float*)d_in[0];
    const int*   srcN = (const int*)d_in[1];
    const int*   dstE = (const int*)d_in[2];
    const float* norm = (const float*)d_in[3];
    const float* elng = (const float*)d_in[4];
    const float* elnb = (const float*)d_in[5];
    const float* eW   = (const float*)d_in[6];
    const float* eB   = (const float*)d_in[7];
    const float* dW   = (const float*)d_in[8];
    const float* dB   = (const float*)d_in[9];
    const float* W1   = (const float*)d_in[10];
    const float* b1   = (const float*)d_in[11];
    const float* clng = (const float*)d_in[12];
    const float* clnb = (const float*)d_in[13];
    const float* W2   = (const float*)d_in[14];
    const float* b2   = (const float*)d_in[15];

    const int N = in_sizes[0] / 128;
    const int E = in_sizes[1];
    const int M = (out_size - N * 128) / 130;

    // workspace carve
    char* p = (char*)d_ws;
    auto carve = [&](size_t bytes) { void* q = (void*)p; p += ((bytes + 255) / 256) * 256; return q; };
    int*   minv  = (int*)carve(4);
    int*   cntM  = (int*)carve((size_t)M * 4);
    int*   cntN  = (int*)carve((size_t)N * 4);
    int*   rpM   = (int*)carve((size_t)(M + 1) * 4);
    int*   rpN   = (int*)carve((size_t)(N + 1) * 4);
    int*   csrD  = (int*)carve((size_t)E * 4);
    int*   csrS  = (int*)carve((size_t)E * 4);
    float* stats = (float*)carve(132 * 4);
    float* hbuf  = (float*)carve((size_t)N * 128 * 4);
    float* aggb  = (float*)carve((size_t)N * 128 * 4);
    float* e0    = (float*)carve((size_t)M * 128 * 4);
    float* e1    = (float*)carve((size_t)M * 128 * 4);

    float* outf      = (float*)d_out;
    float* score     = outf;                                   // [M,2]
    float* edge_feat = outf + (size_t)M * 2;                   // [M,128]
    float* node_feat = outf + (size_t)M * 2 + (size_t)M * 128; // [N,128]

    // ---- graph structure (CSR by dst and by src)
    hipMemsetAsync(minv, 0x7f, 4, stream);
    hipMemsetAsync(cntM, 0, (size_t)M * 4, stream);
    hipMemsetAsync(cntN, 0, (size_t)N * 4, stream);
    k_min<<<256, 256, 0, stream>>>(dstE, E, minv);
    k_count<<<(E + 255) / 256, 256, 0, stream>>>(dstE, srcN, minv, E, cntM, cntN);
    k_scan<<<1, 1024, 0, stream>>>(cntM, M, rpM);
    k_scan<<<1, 1024, 0, stream>>>(cntN, N, rpN);
    hipMemsetAsync(cntM, 0, (size_t)M * 4, stream);
    hipMemsetAsync(cntN, 0, (size_t)N * 4, stream);
    k_fill<<<(E + 255) / 256, 256, 0, stream>>>(dstE, srcN, minv, E, rpM, cntM, csrD, rpN, cntN, csrS);

    // ---- one half-conv: enc(LN->matmul->relu) -> CSR-mean agg -> dec(matmul->relu) -> center_scale -> dest
    auto conv = [&](const float* inbuf, int S, int T, int k, int v2e, float* dest) {
        k_mm128<<<(S + 15) / 16, 256, 0, stream>>>(
            inbuf, S, (k > 0) ? 1 : 0, 1,
            elng + (size_t)k * 128, elnb + (size_t)k * 128,
            eW + (size_t)k * 128 * 128, eB + (size_t)k * 128, hbuf);
        if (v2e)
            k_aggregate<<<(T + 3) / 4, 256, 0, stream>>>(hbuf, rpM, csrD, srcN, minv, 0, norm, aggb, T);
        else
            k_aggregate<<<(T + 3) / 4, 256, 0, stream>>>(hbuf, rpN, csrS, dstE, minv, 1, norm, aggb, T);
        k_mm128<<<(T + 15) / 16, 256, 0, stream>>>(
            aggb, T, 0, 0, nullptr, nullptr,
            dW + (size_t)k * 128 * 128, dB + (size_t)k * 128, hbuf);
        hipMemsetAsync(stats, 0, 129 * 4, stream);
        k_colstats<<<256, 256, 0, stream>>>(hbuf, T, stats);
        k_finalize<<<1, 128, 0, stream>>>(stats, T);
        size_t tot4 = ((size_t)T * 128) / 4;
        k_apply<<<(unsigned)((tot4 + 255) / 256), 256, 0, stream>>>(hbuf, stats, dest, T);
    };

    conv(x,         N, M, 0, 1, e0);         // V2E0
    conv(e0,        M, N, 1, 0, node_feat);  // E2V0 (nf1 parked in node_feat region)
    conv(node_feat, N, M, 2, 1, e1);         // V2E1
    conv(e1,        M, N, 3, 0, node_feat);  // E2V1 -> final node_feat
    conv(node_feat, N, M, 4, 1, edge_feat);  // V2E2 -> final edge_feat

    k_classifier<<<(M + 7) / 8, 256, 0, stream>>>(
        e0, e1, edge_feat, W1, b1, clng, clnb, W2, b2, score, M);
}

// Round 2
// 1443.983 us; speedup vs baseline: 1.3809x; 1.3809x over previous
//
#include <hip/hip_runtime.h>
#include <math.h>

#define BNS 0.9999950000374997f  /* 1/sqrt(1+1e-5) */

// ---------------------------------------------------------------- utilities
static __device__ __forceinline__ float wredf(float v) {
    #pragma unroll
    for (int o = 32; o; o >>= 1) v += __shfl_xor(v, o);
    return v;
}

static __device__ __forceinline__ unsigned short f2bf(float f) {
    unsigned int u = __float_as_uint(f);
    u = (u + 0x7fffu + ((u >> 16) & 1u)) >> 16;  // RNE
    return (unsigned short)u;
}

// ---------------------------------------------------------------- min of dst
__global__ void k_min(const int* __restrict__ d, int E, int* __restrict__ mn) {
    int i = blockIdx.x * blockDim.x + threadIdx.x;
    int v = 0x7FFFFFFF;
    for (; i < E; i += gridDim.x * blockDim.x) v = min(v, d[i]);
    #pragma unroll
    for (int o = 32; o; o >>= 1) v = min(v, __shfl_xor(v, o));
    if ((threadIdx.x & 63) == 0) atomicMin(mn, v);
}

// ---------------------------------------------------------------- histogram
__global__ void k_count(const int* __restrict__ dst, const int* __restrict__ src,
                        const int* __restrict__ minbuf, int E,
                        int* __restrict__ cntM, int* __restrict__ cntN) {
    int i = blockIdx.x * blockDim.x + threadIdx.x;
    if (i >= E) return;
    int mn = minbuf[0];
    atomicAdd(&cntM[dst[i] - mn], 1);
    atomicAdd(&cntN[src[i]], 1);
}

// ---------------------------------------------------------------- exclusive scan (single block, 1024 thr, wave-based)
__global__ __launch_bounds__(1024) void k_scan(const int* __restrict__ cnt, int n,
                                               int* __restrict__ rowptr) {
    __shared__ int wsum[16];
    __shared__ int carry;
    int tid = threadIdx.x, lane = tid & 63, wv = tid >> 6;
    if (tid == 0) carry = 0;
    __syncthreads();
    for (int base = 0; base < n; base += 1024) {
        int i = base + tid;
        int v = (i < n) ? cnt[i] : 0;
        int x = v;
        #pragma unroll
        for (int o = 1; o < 64; o <<= 1) { int t = __shfl_up(x, o); if (lane >= o) x += t; }
        if (lane == 63) wsum[wv] = x;
        __syncthreads();
        if (tid < 16) {
            int s = wsum[tid];
            #pragma unroll
            for (int o = 1; o < 16; o <<= 1) { int t = __shfl_up(s, o); if (tid >= o) s += t; }
            wsum[tid] = s;
        }
        __syncthreads();
        int woff = (wv == 0) ? 0 : wsum[wv - 1];
        int excl = carry + woff + x - v;
        if (i < n) rowptr[i] = excl;
        __syncthreads();
        if (tid == 1023) carry = carry + wsum[15];
        __syncthreads();
    }
    if (tid == 0) rowptr[n] = carry;
}

// ---------------------------------------------------------------- CSR fill: writes fused (gather_row, norm) pairs
__global__ void k_fill(const int* __restrict__ dst, const int* __restrict__ src,
                       const int* __restrict__ minbuf, const float* __restrict__ norm, int E,
                       const int* __restrict__ rpM, int* __restrict__ curM, int2* __restrict__ pairD,
                       const int* __restrict__ rpN, int* __restrict__ curN, int2* __restrict__ pairS) {
    int i = blockIdx.x * blockDim.x + threadIdx.x;
    if (i >= E) return;
    int mn = minbuf[0];
    int w = __float_as_int(norm[i]);
    int d = dst[i] - mn;
    int s = src[i];
    int p = rpM[d] + atomicAdd(&curM[d], 1);
    pairD[p] = make_int2(s, w);          // V2E: gather from src-node rows
    int q = rpN[s] + atomicAdd(&curN[s], 1);
    pairS[q] = make_int2(d, w);          // E2V: gather from edge rows
}

// ---------------------------------------------------------------- fused (preop -> LN) -> 128x128 matmul -> +bias -> relu
// 256 threads, 16 rows per block. A staged in LDS; thread owns (col, 8 rows).
// out_bf16: write ushort bf16 rows (gather source) instead of fp32.
__global__ __launch_bounds__(256) void k_mm128(
        const float* __restrict__ in, int S,
        int preop, int do_ln, int out_bf16,
        const float* __restrict__ lng, const float* __restrict__ lnb,
        const float* __restrict__ W, const float* __restrict__ bias,
        void* __restrict__ outv) {
    __shared__ float A[16][128];
    int tid = threadIdx.x, lane = tid & 63, wv = tid >> 6;
    int base = blockIdx.x * 16;
    #pragma unroll
    for (int i = 0; i < 4; i++) {
        int r = wv * 4 + i, row = base + r;
        float2 v = make_float2(0.f, 0.f);
        if (row < S) v = *(const float2*)(in + (size_t)row * 128 + (lane << 1));
        if (preop) { v.x = fmaxf(v.x * BNS, 0.f); v.y = fmaxf(v.y * BNS, 0.f); }
        if (do_ln) {
            float s = v.x + v.y, q = v.x * v.x + v.y * v.y;
            s = wredf(s); q = wredf(q);
            float m  = s * (1.f / 128.f);
            float var = q * (1.f / 128.f) - m * m;
            float rs = rsqrtf(var + 1e-5f);
            int c = lane << 1;
            v.x = (v.x - m) * rs * lng[c]     + lnb[c];
            v.y = (v.y - m) * rs * lng[c + 1] + lnb[c + 1];
        }
        A[r][lane * 2]     = v.x;
        A[r][lane * 2 + 1] = v.y;
    }
    __syncthreads();
    int col = tid & 127, half = tid >> 7;
    float acc[8];
    #pragma unroll
    for (int r = 0; r < 8; r++) acc[r] = 0.f;
    for (int k = 0; k < 128; k += 4) {
        float w0 = W[(k + 0) * 128 + col];
        float w1 = W[(k + 1) * 128 + col];
        float w2 = W[(k + 2) * 128 + col];
        float w3 = W[(k + 3) * 128 + col];
        #pragma unroll
        for (int r = 0; r < 8; r++) {
            const float4 a = *(const float4*)&A[half * 8 + r][k];
            acc[r] = fmaf(a.x, w0, fmaf(a.y, w1, fmaf(a.z, w2, fmaf(a.w, w3, acc[r]))));
        }
    }
    float bb = bias[col];
    if (out_bf16) {
        unsigned short* out = (unsigned short*)outv;
        #pragma unroll
        for (int r = 0; r < 8; r++) {
            int row = base + half * 8 + r;
            if (row < S) out[(size_t)row * 128 + col] = f2bf(fmaxf(acc[r] + bb, 0.f));
        }
    } else {
        float* out = (float*)outv;
        #pragma unroll
        for (int r = 0; r < 8; r++) {
            int row = base + half * 8 + r;
            if (row < S) out[(size_t)row * 128 + col] = fmaxf(acc[r] + bb, 0.f);
        }
    }
}

// ---------------------------------------------------------------- CSR gather aggregation (norm-weighted mean), bf16 source
__global__ __launch_bounds__(256) void k_aggregate(
        const unsigned short* __restrict__ h, const int* __restrict__ rowptr,
        const int2* __restrict__ pairs, float* __restrict__ agg, int T) {
    int row = blockIdx.x * 4 + (threadIdx.x >> 6);
    if (row >= T) return;
    int lane = threadIdx.x & 63;
    int beg = rowptr[row], end = rowptr[row + 1];
    float a0 = 0.f, a1 = 0.f;
    #pragma unroll 4
    for (int p = beg; p < end; ++p) {
        int2 pr = pairs[p];
        unsigned int v = *(const unsigned int*)(h + (size_t)pr.x * 128 + (lane << 1));
        float w = __int_as_float(pr.y);
        float lo = __uint_as_float(v << 16);
        float hi = __uint_as_float(v & 0xffff0000u);
        a0 = fmaf(w, lo, a0);
        a1 = fmaf(w, hi, a1);
    }
    float invc = 1.f / fmaxf((float)(end - beg), 1.f);
    float2 o; o.x = a0 * invc; o.y = a1 * invc;
    *(float2*)(agg + (size_t)row * 128 + (lane << 1)) = o;
}

// ---------------------------------------------------------------- column stats (colsum[128] + total sumsq at [128])
__global__ __launch_bounds__(256) void k_colstats(const float* __restrict__ x, int n,
                                                  float* __restrict__ stats) {
    int c = threadIdx.x & 127;
    int r = blockIdx.x * 2 + (threadIdx.x >> 7);
    float acc = 0.f, asq = 0.f;
    for (; r < n; r += gridDim.x * 2) {
        float v = x[(size_t)r * 128 + c];
        acc += v; asq += v * v;
    }
    atomicAdd(&stats[c], acc);
    __shared__ float red[4];
    asq = wredf(asq);
    if ((threadIdx.x & 63) == 0) red[threadIdx.x >> 6] = asq;
    __syncthreads();
    if (threadIdx.x == 0) atomicAdd(&stats[128], red[0] + red[1] + red[2] + red[3]);
}

// ---------------------------------------------------------------- finalize center_scale stats: mu[c] in-place, inv at [128]
__global__ void k_finalize(float* __restrict__ stats, int n) {
    int c = threadIdx.x;  // 128 threads
    float mu = stats[c] / (float)n;
    stats[c] = mu;
    float m2 = mu * mu;
    #pragma unroll
    for (int o = 32; o; o >>= 1) m2 += __shfl_xor(m2, o);
    __shared__ float ws2[2];
    if ((c & 63) == 0) ws2[c >> 6] = m2;
    __syncthreads();
    if (c == 0) {
        float musq = ws2[0] + ws2[1];
        float msn = stats[128] / (float)n - musq;  // mean ||x_i - mu||^2
        stats[128] = rsqrtf(1e-5f + msn);
    }
}

// ---------------------------------------------------------------- apply center_scale
__global__ void k_apply(const float* __restrict__ in, const float* __restrict__ stats,
                        float* __restrict__ out, int n) {
    size_t i = ((size_t)blockIdx.x * blockDim.x + threadIdx.x) * 4;
    size_t tot = (size_t)n * 128;
    if (i >= tot) return;
    float inv = stats[128];
    int c = (int)(i & 127);
    float4 v = *(const float4*)(in + i);
    v.x = (v.x - stats[c])     * inv;
    v.y = (v.y - stats[c + 1]) * inv;
    v.z = (v.z - stats[c + 2]) * inv;
    v.w = (v.w - stats[c + 3]) * inv;
    *(float4*)(out + i) = v;
}

// ---------------------------------------------------------------- classifier: [M,384]@[384,256] + b -> LN -> relu -> @[256,2] + b
__global__ __launch_bounds__(256) void k_classifier(
        const float* __restrict__ e0, const float* __restrict__ e1, const float* __restrict__ e2,
        const float* __restrict__ W1, const float* __restrict__ b1,
        const float* __restrict__ lng, const float* __restrict__ lnb,
        const float* __restrict__ W2, const float* __restrict__ b2,
        float* __restrict__ out, int M) {
    __shared__ float A[8][384];
    __shared__ float SC[8][256];
    int tid = threadIdx.x;
    int base = blockIdx.x * 8;
    for (int idx = tid; idx < 8 * 384; idx += 256) {
        int r = idx / 384, c = idx % 384;
        int row = base + r;
        float v = 0.f;
        if (row < M) {
            if (c < 128)      v = e0[(size_t)row * 128 + c];
            else if (c < 256) v = e1[(size_t)row * 128 + (c - 128)];
            else              v = e2[(size_t)row * 128 + (c - 256)];
        }
        A[r][c] = v;
    }
    __syncthreads();
    int j = tid;  // 0..255
    float acc[8];
    #pragma unroll
    for (int r = 0; r < 8; r++) acc[r] = 0.f;
    for (int k = 0; k < 384; k += 4) {
        float w0 = W1[(size_t)(k + 0) * 256 + j];
        float w1 = W1[(size_t)(k + 1) * 256 + j];
        float w2 = W1[(size_t)(k + 2) * 256 + j];
        float w3 = W1[(size_t)(k + 3) * 256 + j];
        #pragma unroll
        for (int r = 0; r < 8; r++) {
            const float4 a = *(const float4*)&A[r][k];
            acc[r] = fmaf(a.x, w0, fmaf(a.y, w1, fmaf(a.z, w2, fmaf(a.w, w3, acc[r]))));
        }
    }
    float bb = b1[j];
    #pragma unroll
    for (int r = 0; r < 8; r++) SC[r][j] = acc[r] + bb;
    __syncthreads();
    int wv = tid >> 6, lane = tid & 63;
    #pragma unroll
    for (int rr = 0; rr < 2; rr++) {
        int r = wv * 2 + rr;
        int row = base + r;
        float v0 = SC[r][lane], v1 = SC[r][lane + 64], v2 = SC[r][lane + 128], v3 = SC[r][lane + 192];
        float s = wredf(v0 + v1 + v2 + v3);
        float q = wredf(v0 * v0 + v1 * v1 + v2 * v2 + v3 * v3);
        float m = s * (1.f / 256.f);
        float var = q * (1.f / 256.f) - m * m;
        float rs = rsqrtf(var + 1e-5f);
        float h0 = fmaxf((v0 - m) * rs * lng[lane]       + lnb[lane],       0.f);
        float h1 = fmaxf((v1 - m) * rs * lng[lane + 64]  + lnb[lane + 64],  0.f);
        float h2 = fmaxf((v2 - m) * rs * lng[lane + 128] + lnb[lane + 128], 0.f);
        float h3 = fmaxf((v3 - m) * rs * lng[lane + 192] + lnb[lane + 192], 0.f);
        float p0 = h0 * W2[lane * 2]           + h1 * W2[(lane + 64) * 2]
                 + h2 * W2[(lane + 128) * 2]   + h3 * W2[(lane + 192) * 2];
        float p1 = h0 * W2[lane * 2 + 1]       + h1 * W2[(lane + 64) * 2 + 1]
                 + h2 * W2[(lane + 128) * 2 + 1] + h3 * W2[(lane + 192) * 2 + 1];
        p0 = wredf(p0);
        p1 = wredf(p1);
        if (lane == 0 && row < M) {
            out[(size_t)row * 2]     = p0 + b2[0];
            out[(size_t)row * 2 + 1] = p1 + b2[1];
        }
    }
}

// ================================================================ host
extern "C" void kernel_launch(void* const* d_in, const int* in_sizes, int n_in,
                              void* d_out, int out_size, void* d_ws, size_t ws_size,
                              hipStream_t stream) {
    const float* x    = (const float*)d_in[0];
    const int*   srcN = (const int*)d_in[1];
    const int*   dstE = (const int*)d_in[2];
    const float* norm = (const float*)d_in[3];
    const float* elng = (const float*)d_in[4];
    const float* elnb = (const float*)d_in[5];
    const float* eW   = (const float*)d_in[6];
    const float* eB   = (const float*)d_in[7];
    const float* dW   = (const float*)d_in[8];
    const float* dB   = (const float*)d_in[9];
    const float* W1   = (const float*)d_in[10];
    const float* b1   = (const float*)d_in[11];
    const float* clng = (const float*)d_in[12];
    const float* clnb = (const float*)d_in[13];
    const float* W2   = (const float*)d_in[14];
    const float* b2   = (const float*)d_in[15];

    const int N = in_sizes[0] / 128;
    const int E = in_sizes[1];
    const int M = (out_size - N * 128) / 130;

    // workspace carve
    char* p = (char*)d_ws;
    auto carve = [&](size_t bytes) { void* q = (void*)p; p += ((bytes + 255) / 256) * 256; return q; };
    int*   minv  = (int*)carve(4);
    int*   cntM  = (int*)carve((size_t)M * 4);
    int*   cntN  = (int*)carve((size_t)N * 4);
    int*   rpM   = (int*)carve((size_t)(M + 1) * 4);
    int*   rpN   = (int*)carve((size_t)(N + 1) * 4);
    int2*  pairD = (int2*)carve((size_t)E * 8);
    int2*  pairS = (int2*)carve((size_t)E * 8);
    float* stats = (float*)carve(132 * 4);
    float* hbuf  = (float*)carve((size_t)N * 128 * 4);   // dec output (fp32); also overlays enc bf16 output
    float* aggb  = (float*)carve((size_t)N * 128 * 4);
    float* e0    = (float*)carve((size_t)M * 128 * 4);
    float* e1    = (float*)carve((size_t)M * 128 * 4);
    unsigned short* hb16 = (unsigned short*)hbuf;        // enc bf16 rows; dead before dec writes hbuf

    float* outf      = (float*)d_out;
    float* score     = outf;                                   // [M,2]
    float* edge_feat = outf + (size_t)M * 2;                   // [M,128]
    float* node_feat = outf + (size_t)M * 2 + (size_t)M * 128; // [N,128]

    // ---- graph structure (CSR by dst and by src, with fused (row,norm) pairs)
    hipMemsetAsync(minv, 0x7f, 4, stream);
    hipMemsetAsync(cntM, 0, (size_t)M * 4, stream);
    hipMemsetAsync(cntN, 0, (size_t)N * 4, stream);
    k_min<<<256, 256, 0, stream>>>(dstE, E, minv);
    k_count<<<(E + 255) / 256, 256, 0, stream>>>(dstE, srcN, minv, E, cntM, cntN);
    k_scan<<<1, 1024, 0, stream>>>(cntM, M, rpM);
    k_scan<<<1, 1024, 0, stream>>>(cntN, N, rpN);
    hipMemsetAsync(cntM, 0, (size_t)M * 4, stream);
    hipMemsetAsync(cntN, 0, (size_t)N * 4, stream);
    k_fill<<<(E + 255) / 256, 256, 0, stream>>>(dstE, srcN, minv, norm, E,
                                                rpM, cntM, pairD, rpN, cntN, pairS);

    // ---- one half-conv: enc(LN->matmul->relu->bf16) -> CSR-mean agg -> dec(matmul->relu) -> center_scale -> dest
    auto conv = [&](const float* inbuf, int S, int T, int k, int v2e, float* dest) {
        k_mm128<<<(S + 15) / 16, 256, 0, stream>>>(
            inbuf, S, (k > 0) ? 1 : 0, 1, 1,
            elng + (size_t)k * 128, elnb + (size_t)k * 128,
            eW + (size_t)k * 128 * 128, eB + (size_t)k * 128, hb16);
        if (v2e)
            k_aggregate<<<(T + 3) / 4, 256, 0, stream>>>(hb16, rpM, pairD, aggb, T);
        else
            k_aggregate<<<(T + 3) / 4, 256, 0, stream>>>(hb16, rpN, pairS, aggb, T);
        k_mm128<<<(T + 15) / 16, 256, 0, stream>>>(
            aggb, T, 0, 0, 0, nullptr, nullptr,
            dW + (size_t)k * 128 * 128, dB + (size_t)k * 128, hbuf);
        hipMemsetAsync(stats, 0, 129 * 4, stream);
        k_colstats<<<256, 256, 0, stream>>>(hbuf, T, stats);
        k_finalize<<<1, 128, 0, stream>>>(stats, T);
        size_t tot4 = ((size_t)T * 128) / 4;
        k_apply<<<(unsigned)((tot4 + 255) / 256), 256, 0, stream>>>(hbuf, stats, dest, T);
    };

    conv(x,         N, M, 0, 1, e0);         // V2E0
    conv(e0,        M, N, 1, 0, node_feat);  // E2V0 (nf1 parked in node_feat region)
    conv(node_feat, N, M, 2, 1, e1);         // V2E1
    conv(e1,        M, N, 3, 0, node_feat);  // E2V1 -> final node_feat
    conv(node_feat, N, M, 4, 1, edge_feat);  // V2E2 -> final edge_feat

    k_classifier<<<(M + 7) / 8, 256, 0, stream>>>(
        e0, e1, edge_feat, W1, b1, clng, clnb, W2, b2, score, M);
}

// Round 3
// 1293.613 us; speedup vs baseline: 1.5414x; 1.1162x over previous
//
#include <hip/hip_runtime.h>
#include <math.h>

#define BNS 0.9999950000374997f  /* 1/sqrt(1+1e-5) */

typedef short s8v __attribute__((ext_vector_type(8)));
typedef float f4v __attribute__((ext_vector_type(4)));

// ---------------------------------------------------------------- utilities
static __device__ __forceinline__ float wredf(float v) {
    #pragma unroll
    for (int o = 32; o; o >>= 1) v += __shfl_xor(v, o);
    return v;
}

static __device__ __forceinline__ unsigned short f2bf(float f) {
    unsigned int u = __float_as_uint(f);
    u = (u + 0x7fffu + ((u >> 16) & 1u)) >> 16;  // RNE
    return (unsigned short)u;
}

static __device__ __forceinline__ float bf2f(unsigned short b) {
    return __uint_as_float((unsigned int)b << 16);
}

static __device__ __forceinline__ f4v mfma16(s8v a, s8v b, f4v c) {
    return __builtin_amdgcn_mfma_f32_16x16x32_bf16(a, b, c, 0, 0, 0);
}

// ---------------------------------------------------------------- min of dst
__global__ void k_min(const int* __restrict__ d, int E, int* __restrict__ mn) {
    int i = blockIdx.x * blockDim.x + threadIdx.x;
    int v = 0x7FFFFFFF;
    for (; i < E; i += gridDim.x * blockDim.x) v = min(v, d[i]);
    #pragma unroll
    for (int o = 32; o; o >>= 1) v = min(v, __shfl_xor(v, o));
    if ((threadIdx.x & 63) == 0) atomicMin(mn, v);
}

// ---------------------------------------------------------------- histogram
__global__ void k_count(const int* __restrict__ dst, const int* __restrict__ src,
                        const int* __restrict__ minbuf, int E,
                        int* __restrict__ cntM, int* __restrict__ cntN) {
    int i = blockIdx.x * blockDim.x + threadIdx.x;
    if (i >= E) return;
    int mn = minbuf[0];
    atomicAdd(&cntM[dst[i] - mn], 1);
    atomicAdd(&cntN[src[i]], 1);
}

// ---------------------------------------------------------------- exclusive scan (single block, 1024 thr, wave-based)
__global__ __launch_bounds__(1024) void k_scan(const int* __restrict__ cnt, int n,
                                               int* __restrict__ rowptr) {
    __shared__ int wsum[16];
    __shared__ int carry;
    int tid = threadIdx.x, lane = tid & 63, wv = tid >> 6;
    if (tid == 0) carry = 0;
    __syncthreads();
    for (int base = 0; base < n; base += 1024) {
        int i = base + tid;
        int v = (i < n) ? cnt[i] : 0;
        int x = v;
        #pragma unroll
        for (int o = 1; o < 64; o <<= 1) { int t = __shfl_up(x, o); if (lane >= o) x += t; }
        if (lane == 63) wsum[wv] = x;
        __syncthreads();
        if (tid < 16) {
            int s = wsum[tid];
            #pragma unroll
            for (int o = 1; o < 16; o <<= 1) { int t = __shfl_up(s, o); if (tid >= o) s += t; }
            wsum[tid] = s;
        }
        __syncthreads();
        int woff = (wv == 0) ? 0 : wsum[wv - 1];
        int excl = carry + woff + x - v;
        if (i < n) rowptr[i] = excl;
        __syncthreads();
        if (tid == 1023) carry = carry + wsum[15];
        __syncthreads();
    }
    if (tid == 0) rowptr[n] = carry;
}

// ---------------------------------------------------------------- CSR fill: writes fused (gather_row, norm) pairs
__global__ void k_fill(const int* __restrict__ dst, const int* __restrict__ src,
                       const int* __restrict__ minbuf, const float* __restrict__ norm, int E,
                       const int* __restrict__ rpM, int* __restrict__ curM, int2* __restrict__ pairD,
                       const int* __restrict__ rpN, int* __restrict__ curN, int2* __restrict__ pairS) {
    int i = blockIdx.x * blockDim.x + threadIdx.x;
    if (i >= E) return;
    int mn = minbuf[0];
    int w = __float_as_int(norm[i]);
    int d = dst[i] - mn;
    int s = src[i];
    int p = rpM[d] + atomicAdd(&curM[d], 1);
    pairD[p] = make_int2(s, w);          // V2E: gather from src-node rows
    int q = rpN[s] + atomicAdd(&curN[s], 1);
    pairS[q] = make_int2(d, w);          // E2V: gather from edge rows
}

// ---------------------------------------------------------------- weight prep: fp32 [K][Nn] -> bf16 hi/lo [Nn][K] (transposed)
__global__ void k_prepT(const float* __restrict__ in, int nmat, int K, int Nn,
                        unsigned short* __restrict__ oh, unsigned short* __restrict__ ol) {
    int total = nmat * K * Nn;
    for (int i = blockIdx.x * blockDim.x + threadIdx.x; i < total; i += gridDim.x * blockDim.x) {
        int m = i / (K * Nn), r = i % (K * Nn);
        int k = r / Nn, n = r % Nn;
        float v = in[i];
        unsigned short hb = f2bf(v);
        float lo = v - bf2f(hb);
        size_t o = (size_t)m * K * Nn + (size_t)n * K + k;
        oh[o] = hb;
        ol[o] = f2bf(lo);
    }
}

// ---------------------------------------------------------------- MFMA split-bf16: (preop -> LN) -> [S,128]@[128,128] -> +bias -> relu
// 256 thr = 4 waves; 128 rows/block; wave owns 32 rows (2 m-tiles x 8 n-tiles).
__global__ __launch_bounds__(256) void k_mmfma(
        const float* __restrict__ in, int S, int preop, int do_ln,
        const float* __restrict__ lng, const float* __restrict__ lnb,
        const unsigned short* __restrict__ wth, const unsigned short* __restrict__ wtl,
        const float* __restrict__ bias, int out_bf16, void* __restrict__ outv) {
    int lane = threadIdx.x & 63, wv = threadIdx.x >> 6;
    int rbase = blockIdx.x * 128 + wv * 32;
    int g = lane >> 4;          // k-group 0..3
    int rm = lane & 15;         // A-row within tile / C-col
    s8v ah[2][4], al[2][4];
    #pragma unroll
    for (int mt = 0; mt < 2; mt++) {
        int row = rbase + mt * 16 + rm;
        const float* rp = in + (size_t)row * 128 + g * 8;
        bool ok = row < S;
        float v[4][8];
        float s = 0.f, q = 0.f;
        #pragma unroll
        for (int ks = 0; ks < 4; ks++) {
            float4 p0 = make_float4(0.f,0.f,0.f,0.f), p1 = make_float4(0.f,0.f,0.f,0.f);
            if (ok) { p0 = *(const float4*)(rp + ks * 32); p1 = *(const float4*)(rp + ks * 32 + 4); }
            float t[8] = {p0.x,p0.y,p0.z,p0.w,p1.x,p1.y,p1.z,p1.w};
            #pragma unroll
            for (int j = 0; j < 8; j++) {
                float x = t[j];
                if (preop) x = fmaxf(x * BNS, 0.f);
                v[ks][j] = x;
                s += x; q += x * x;
            }
        }
        float m = 0.f, rs = 1.f;
        if (do_ln) {
            s += __shfl_xor(s, 16); s += __shfl_xor(s, 32);
            q += __shfl_xor(q, 16); q += __shfl_xor(q, 32);
            m = s * (1.f / 128.f);
            float var = q * (1.f / 128.f) - m * m;
            rs = rsqrtf(var + 1e-5f);
        }
        #pragma unroll
        for (int ks = 0; ks < 4; ks++) {
            float w[8];
            if (do_ln) {
                const float4 g0 = *(const float4*)(lng + ks * 32 + g * 8);
                const float4 g1 = *(const float4*)(lng + ks * 32 + g * 8 + 4);
                const float4 b0 = *(const float4*)(lnb + ks * 32 + g * 8);
                const float4 b1 = *(const float4*)(lnb + ks * 32 + g * 8 + 4);
                float gg[8] = {g0.x,g0.y,g0.z,g0.w,g1.x,g1.y,g1.z,g1.w};
                float bb[8] = {b0.x,b0.y,b0.z,b0.w,b1.x,b1.y,b1.z,b1.w};
                #pragma unroll
                for (int j = 0; j < 8; j++) w[j] = (v[ks][j] - m) * rs * gg[j] + bb[j];
            } else {
                #pragma unroll
                for (int j = 0; j < 8; j++) w[j] = v[ks][j];
            }
            #pragma unroll
            for (int j = 0; j < 8; j++) {
                unsigned short hb = f2bf(w[j]);
                ah[mt][ks][j] = (short)hb;
                al[mt][ks][j] = (short)f2bf(w[j] - bf2f(hb));
            }
        }
    }
    f4v acc[2][8] = {};
    #pragma unroll
    for (int ks = 0; ks < 4; ks++) {
        #pragma unroll
        for (int nt = 0; nt < 8; nt++) {
            size_t wo = (size_t)(nt * 16 + rm) * 128 + ks * 32 + g * 8;
            s8v bh = *(const s8v*)(wth + wo);
            s8v bl = *(const s8v*)(wtl + wo);
            #pragma unroll
            for (int mt = 0; mt < 2; mt++) {
                acc[mt][nt] = mfma16(ah[mt][ks], bh, acc[mt][nt]);
                acc[mt][nt] = mfma16(al[mt][ks], bh, acc[mt][nt]);
                acc[mt][nt] = mfma16(ah[mt][ks], bl, acc[mt][nt]);
            }
        }
    }
    #pragma unroll
    for (int nt = 0; nt < 8; nt++) {
        float bb = bias[nt * 16 + rm];
        #pragma unroll
        for (int mt = 0; mt < 2; mt++) {
            #pragma unroll
            for (int r = 0; r < 4; r++) {
                int row = rbase + mt * 16 + g * 4 + r;   // C row mapping
                float val = fmaxf(acc[mt][nt][r] + bb, 0.f);
                if (out_bf16) {
                    unsigned int bits = f2bf(val);
                    unsigned int pb = (unsigned int)__shfl_xor((int)bits, 1);
                    if (!(lane & 1) && row < S) {
                        unsigned int word = bits | (pb << 16);
                        ((unsigned int*)outv)[((size_t)row * 128 + nt * 16 + rm) >> 1] = word;
                    }
                } else {
                    if (row < S) ((float*)outv)[(size_t)row * 128 + nt * 16 + rm] = val;
                }
            }
        }
    }
}

// ---------------------------------------------------------------- CSR gather aggregation (norm-weighted mean), bf16 source
__global__ __launch_bounds__(256) void k_aggregate(
        const unsigned short* __restrict__ h, const int* __restrict__ rowptr,
        const int2* __restrict__ pairs, float* __restrict__ agg, int T) {
    int row = blockIdx.x * 4 + (threadIdx.x >> 6);
    if (row >= T) return;
    int lane = threadIdx.x & 63;
    int beg = rowptr[row], end = rowptr[row + 1];
    float a0 = 0.f, a1 = 0.f;
    #pragma unroll 4
    for (int p = beg; p < end; ++p) {
        int2 pr = pairs[p];
        unsigned int v = *(const unsigned int*)(h + (size_t)pr.x * 128 + (lane << 1));
        float w = __int_as_float(pr.y);
        float lo = __uint_as_float(v << 16);
        float hi = __uint_as_float(v & 0xffff0000u);
        a0 = fmaf(w, lo, a0);
        a1 = fmaf(w, hi, a1);
    }
    float invc = 1.f / fmaxf((float)(end - beg), 1.f);
    float2 o; o.x = a0 * invc; o.y = a1 * invc;
    *(float2*)(agg + (size_t)row * 128 + (lane << 1)) = o;
}

// ---------------------------------------------------------------- column stats (colsum[128] + total sumsq at [128])
__global__ __launch_bounds__(256) void k_colstats(const float* __restrict__ x, int n,
                                                  float* __restrict__ stats) {
    int c = threadIdx.x & 127;
    int r = blockIdx.x * 2 + (threadIdx.x >> 7);
    float acc = 0.f, asq = 0.f;
    for (; r < n; r += gridDim.x * 2) {
        float v = x[(size_t)r * 128 + c];
        acc += v; asq += v * v;
    }
    atomicAdd(&stats[c], acc);
    __shared__ float red[4];
    asq = wredf(asq);
    if ((threadIdx.x & 63) == 0) red[threadIdx.x >> 6] = asq;
    __syncthreads();
    if (threadIdx.x == 0) atomicAdd(&stats[128], red[0] + red[1] + red[2] + red[3]);
}

// ---------------------------------------------------------------- finalize center_scale stats: mu[c] in-place, inv at [128]
__global__ void k_finalize(float* __restrict__ stats, int n) {
    int c = threadIdx.x;  // 128 threads
    float mu = stats[c] / (float)n;
    stats[c] = mu;
    float m2 = mu * mu;
    #pragma unroll
    for (int o = 32; o; o >>= 1) m2 += __shfl_xor(m2, o);
    __shared__ float ws2[2];
    if ((c & 63) == 0) ws2[c >> 6] = m2;
    __syncthreads();
    if (c == 0) {
        float musq = ws2[0] + ws2[1];
        float msn = stats[128] / (float)n - musq;  // mean ||x_i - mu||^2
        stats[128] = rsqrtf(1e-5f + msn);
    }
}

// ---------------------------------------------------------------- apply center_scale
__global__ void k_apply(const float* __restrict__ in, const float* __restrict__ stats,
                        float* __restrict__ out, int n) {
    size_t i = ((size_t)blockIdx.x * blockDim.x + threadIdx.x) * 4;
    size_t tot = (size_t)n * 128;
    if (i >= tot) return;
    float inv = stats[128];
    int c = (int)(i & 127);
    float4 v = *(const float4*)(in + i);
    v.x = (v.x - stats[c])     * inv;
    v.y = (v.y - stats[c + 1]) * inv;
    v.z = (v.z - stats[c + 2]) * inv;
    v.w = (v.w - stats[c + 3]) * inv;
    *(float4*)(out + i) = v;
}

// ---------------------------------------------------------------- classifier matmul: [M,384]@[384,256]+b1 -> SC (MFMA split-bf16)
// 256 thr = 4 waves; 64 rows/block; wave owns 16 rows x 16 n-tiles.
__global__ __launch_bounds__(256) void k_cls_mm(
        const float* __restrict__ e0, const float* __restrict__ e1, const float* __restrict__ e2,
        const unsigned short* __restrict__ wth, const unsigned short* __restrict__ wtl,
        const float* __restrict__ b1, float* __restrict__ SC, int M) {
    int lane = threadIdx.x & 63, wv = threadIdx.x >> 6;
    int rbase = blockIdx.x * 64 + wv * 16;
    int g = lane >> 4, rm = lane & 15;
    int row = rbase + rm;
    bool ok = row < M;
    f4v acc[16] = {};
    #pragma unroll
    for (int ks = 0; ks < 12; ks++) {
        const float* src = (ks < 4) ? e0 : (ks < 8) ? e1 : e2;
        const float* rp = src + (size_t)row * 128 + (ks & 3) * 32 + g * 8;
        float4 p0 = make_float4(0.f,0.f,0.f,0.f), p1 = make_float4(0.f,0.f,0.f,0.f);
        if (ok) { p0 = *(const float4*)rp; p1 = *(const float4*)(rp + 4); }
        float t[8] = {p0.x,p0.y,p0.z,p0.w,p1.x,p1.y,p1.z,p1.w};
        s8v ah, al;
        #pragma unroll
        for (int j = 0; j < 8; j++) {
            unsigned short hb = f2bf(t[j]);
            ah[j] = (short)hb;
            al[j] = (short)f2bf(t[j] - bf2f(hb));
        }
        #pragma unroll
        for (int nt = 0; nt < 16; nt++) {
            size_t wo = (size_t)(nt * 16 + rm) * 384 + ks * 32 + g * 8;
            s8v bh = *(const s8v*)(wth + wo);
            s8v bl = *(const s8v*)(wtl + wo);
            acc[nt] = mfma16(ah, bh, acc[nt]);
            acc[nt] = mfma16(al, bh, acc[nt]);
            acc[nt] = mfma16(ah, bl, acc[nt]);
        }
    }
    #pragma unroll
    for (int nt = 0; nt < 16; nt++) {
        float bb = b1[nt * 16 + rm];
        #pragma unroll
        for (int r = 0; r < 4; r++) {
            int rr = rbase + g * 4 + r;
            if (rr < M) SC[(size_t)rr * 256 + nt * 16 + rm] = acc[nt][r] + bb;
        }
    }
}

// ---------------------------------------------------------------- classifier tail: LN -> relu -> @[256,2]+b2
__global__ __launch_bounds__(256) void k_cls_ln(
        const float* __restrict__ SC,
        const float* __restrict__ lng, const float* __restrict__ lnb,
        const float* __restrict__ W2, const float* __restrict__ b2,
        float* __restrict__ out, int M) {
    int row = blockIdx.x * 4 + (threadIdx.x >> 6);
    if (row >= M) return;
    int lane = threadIdx.x & 63;
    const float* sp = SC + (size_t)row * 256;
    float v0 = sp[lane], v1 = sp[lane + 64], v2 = sp[lane + 128], v3 = sp[lane + 192];
    float s = wredf(v0 + v1 + v2 + v3);
    float q = wredf(v0 * v0 + v1 * v1 + v2 * v2 + v3 * v3);
    float m = s * (1.f / 256.f);
    float var = q * (1.f / 256.f) - m * m;
    float rs = rsqrtf(var + 1e-5f);
    float h0 = fmaxf((v0 - m) * rs * lng[lane]       + lnb[lane],       0.f);
    float h1 = fmaxf((v1 - m) * rs * lng[lane + 64]  + lnb[lane + 64],  0.f);
    float h2 = fmaxf((v2 - m) * rs * lng[lane + 128] + lnb[lane + 128], 0.f);
    float h3 = fmaxf((v3 - m) * rs * lng[lane + 192] + lnb[lane + 192], 0.f);
    float p0 = h0 * W2[lane * 2]             + h1 * W2[(lane + 64) * 2]
             + h2 * W2[(lane + 128) * 2]     + h3 * W2[(lane + 192) * 2];
    float p1 = h0 * W2[lane * 2 + 1]         + h1 * W2[(lane + 64) * 2 + 1]
             + h2 * W2[(lane + 128) * 2 + 1] + h3 * W2[(lane + 192) * 2 + 1];
    p0 = wredf(p0);
    p1 = wredf(p1);
    if (lane == 0) {
        out[(size_t)row * 2]     = p0 + b2[0];
        out[(size_t)row * 2 + 1] = p1 + b2[1];
    }
}

// ================================================================ host
extern "C" void kernel_launch(void* const* d_in, const int* in_sizes, int n_in,
                              void* d_out, int out_size, void* d_ws, size_t ws_size,
                              hipStream_t stream) {
    const float* x    = (const float*)d_in[0];
    const int*   srcN = (const int*)d_in[1];
    const int*   dstE = (const int*)d_in[2];
    const float* norm = (const float*)d_in[3];
    const float* elng = (const float*)d_in[4];
    const float* elnb = (const float*)d_in[5];
    const float* eW   = (const float*)d_in[6];
    const float* eB   = (const float*)d_in[7];
    const float* dW   = (const float*)d_in[8];
    const float* dB   = (const float*)d_in[9];
    const float* W1   = (const float*)d_in[10];
    const float* b1   = (const float*)d_in[11];
    const float* clng = (const float*)d_in[12];
    const float* clnb = (const float*)d_in[13];
    const float* W2   = (const float*)d_in[14];
    const float* b2   = (const float*)d_in[15];

    const int N = in_sizes[0] / 128;
    const int E = in_sizes[1];
    const int M = (out_size - N * 128) / 130;

    // workspace carve
    char* p = (char*)d_ws;
    auto carve = [&](size_t bytes) { void* q = (void*)p; p += ((bytes + 255) / 256) * 256; return q; };
    int*   minv  = (int*)carve(4);
    int*   cntM  = (int*)carve((size_t)M * 4);
    int*   cntN  = (int*)carve((size_t)N * 4);
    int*   rpM   = (int*)carve((size_t)(M + 1) * 4);
    int*   rpN   = (int*)carve((size_t)(N + 1) * 4);
    int2*  pairD = (int2*)carve((size_t)E * 8);
    int2*  pairS = (int2*)carve((size_t)E * 8);
    float* stats = (float*)carve(132 * 4);
    unsigned short* encTh = (unsigned short*)carve((size_t)5 * 16384 * 2);
    unsigned short* encTl = (unsigned short*)carve((size_t)5 * 16384 * 2);
    unsigned short* decTh = (unsigned short*)carve((size_t)5 * 16384 * 2);
    unsigned short* decTl = (unsigned short*)carve((size_t)5 * 16384 * 2);
    unsigned short* w1Th  = (unsigned short*)carve((size_t)384 * 256 * 2);
    unsigned short* w1Tl  = (unsigned short*)carve((size_t)384 * 256 * 2);
    float* hbuf  = (float*)carve((size_t)N * 128 * 4);   // dec output (fp32); also overlays enc bf16 output
    float* aggb  = (float*)carve((size_t)N * 128 * 4);   // agg fp32; overlays classifier SC at the end
    float* e0    = (float*)carve((size_t)M * 128 * 4);
    float* e1    = (float*)carve((size_t)M * 128 * 4);
    unsigned short* hb16 = (unsigned short*)hbuf;        // enc bf16 rows; dead before dec writes hbuf
    float* SC = aggb;                                    // [M,256]; aggb dead at classifier time

    float* outf      = (float*)d_out;
    float* score     = outf;                                   // [M,2]
    float* edge_feat = outf + (size_t)M * 2;                   // [M,128]
    float* node_feat = outf + (size_t)M * 2 + (size_t)M * 128; // [N,128]

    // ---- weight prep (transpose + split-bf16)
    k_prepT<<<320, 256, 0, stream>>>(eW, 5, 128, 128, encTh, encTl);
    k_prepT<<<320, 256, 0, stream>>>(dW, 5, 128, 128, decTh, decTl);
    k_prepT<<<384, 256, 0, stream>>>(W1, 1, 384, 256, w1Th, w1Tl);

    // ---- graph structure (CSR by dst and by src, with fused (row,norm) pairs)
    hipMemsetAsync(minv, 0x7f, 4, stream);
    hipMemsetAsync(cntM, 0, (size_t)M * 4, stream);
    hipMemsetAsync(cntN, 0, (size_t)N * 4, stream);
    k_min<<<256, 256, 0, stream>>>(dstE, E, minv);
    k_count<<<(E + 255) / 256, 256, 0, stream>>>(dstE, srcN, minv, E, cntM, cntN);
    k_scan<<<1, 1024, 0, stream>>>(cntM, M, rpM);
    k_scan<<<1, 1024, 0, stream>>>(cntN, N, rpN);
    hipMemsetAsync(cntM, 0, (size_t)M * 4, stream);
    hipMemsetAsync(cntN, 0, (size_t)N * 4, stream);
    k_fill<<<(E + 255) / 256, 256, 0, stream>>>(dstE, srcN, minv, norm, E,
                                                rpM, cntM, pairD, rpN, cntN, pairS);

    // ---- one half-conv: enc(LN->mfma->relu->bf16) -> CSR-mean agg -> dec(mfma->relu) -> center_scale -> dest
    auto conv = [&](const float* inbuf, int S, int T, int k, int v2e, float* dest) {
        k_mmfma<<<(S + 127) / 128, 256, 0, stream>>>(
            inbuf, S, (k > 0) ? 1 : 0, 1,
            elng + (size_t)k * 128, elnb + (size_t)k * 128,
            encTh + (size_t)k * 16384, encTl + (size_t)k * 16384,
            eB + (size_t)k * 128, 1, hb16);
        if (v2e)
            k_aggregate<<<(T + 3) / 4, 256, 0, stream>>>(hb16, rpM, pairD, aggb, T);
        else
            k_aggregate<<<(T + 3) / 4, 256, 0, stream>>>(hb16, rpN, pairS, aggb, T);
        k_mmfma<<<(T + 127) / 128, 256, 0, stream>>>(
            aggb, T, 0, 0,
            elng, elnb,  // unused when do_ln=0
            decTh + (size_t)k * 16384, decTl + (size_t)k * 16384,
            dB + (size_t)k * 128, 0, hbuf);
        hipMemsetAsync(stats, 0, 129 * 4, stream);
        k_colstats<<<256, 256, 0, stream>>>(hbuf, T, stats);
        k_finalize<<<1, 128, 0, stream>>>(stats, T);
        size_t tot4 = ((size_t)T * 128) / 4;
        k_apply<<<(unsigned)((tot4 + 255) / 256), 256, 0, stream>>>(hbuf, stats, dest, T);
    };

    conv(x,         N, M, 0, 1, e0);         // V2E0
    conv(e0,        M, N, 1, 0, node_feat);  // E2V0 (nf1 parked in node_feat region)
    conv(node_feat, N, M, 2, 1, e1);         // V2E1
    conv(e1,        M, N, 3, 0, node_feat);  // E2V1 -> final node_feat
    conv(node_feat, N, M, 4, 1, edge_feat);  // V2E2 -> final edge_feat

    k_cls_mm<<<(M + 63) / 64, 256, 0, stream>>>(e0, e1, edge_feat, w1Th, w1Tl, b1, SC, M);
    k_cls_ln<<<(M + 3) / 4, 256, 0, stream>>>(SC, clng, clnb, W2, b2, score, M);
}